// Round 6
// baseline (167.917 us; speedup 1.0000x reference)
//
#include <hip/hip_runtime.h>
#include <stdint.h>

// x (8, 512, 64, 64) fp32, mask (64, 64) int32 -> out (8, 768, 64, 64) fp32
static constexpr int HW = 4096;   // 64*64
static constexpr int CC = 512;
static constexpr int C2 = 256;
static constexpr int OC = 768;

__device__ __forceinline__ uint32_t rotl32(uint32_t x, int d) {
  return (x << d) | (x >> (32 - d));
}

// JAX threefry2x32, key (0, 42)  [jax.random.key(42)]
__device__ __forceinline__ void threefry_0_42(uint32_t x0, uint32_t x1,
                                              uint32_t& o0, uint32_t& o1) {
  const uint32_t k0 = 0u;
  const uint32_t k1 = 42u;
  const uint32_t k2 = 0x1BD11BDAu ^ k0 ^ k1;   // 0x1BD11BF0
  x0 += k0; x1 += k1;
#define TF_ROUND(r) { x0 += x1; x1 = rotl32(x1, (r)); x1 ^= x0; }
  TF_ROUND(13) TF_ROUND(15) TF_ROUND(26) TF_ROUND(6)
  x0 += k1; x1 += k2 + 1u;
  TF_ROUND(17) TF_ROUND(29) TF_ROUND(16) TF_ROUND(24)
  x0 += k2; x1 += k0 + 2u;
  TF_ROUND(13) TF_ROUND(15) TF_ROUND(26) TF_ROUND(6)
  x0 += k0; x1 += k1 + 3u;
  TF_ROUND(17) TF_ROUND(29) TF_ROUND(16) TF_ROUND(24)
  x0 += k1; x1 += k2 + 4u;
  TF_ROUND(13) TF_ROUND(15) TF_ROUND(26) TF_ROUND(6)
  x0 += k2; x1 += k0 + 5u;
#undef TF_ROUND
  o0 = x0; o1 = x1;
}

// Partitionable threefry: counter (0, e), fold = xor of the two output lanes.
__device__ __forceinline__ uint32_t jax_bits32(uint32_t e) {
  uint32_t o0, o1;
  threefry_0_42(0u, e, o0, o1);
  return o0 ^ o1;
}

// ---------------------------------------------------------------------------
// Kernel A (6144 blocks, 1 copy : 2 argmax interleave for VALU/mem overlap):
//   p%3==0: copy former plane fp=p/3 in [0,2048): out[b,c] = x[b,c]
//   else:   argmax row i = 2*(p/3) + (p%3-1) in [0,4096):
//     flag[i]==0 -> idx[i] = -1 (reference discards this row)
//     else: ballot-compact unflagged columns into LDS (order-independent:
//           packed key ((bits>>9)<<12)|(4095-j) breaks ties to smallest j),
//           then exact integer argmax of partitionable-threefry bits
//           (uniform is monotone in bits>>9).
__global__ __launch_bounds__(256) void former_argmax_kernel(
    const float* __restrict__ x, const int* __restrict__ mask,
    int* __restrict__ idx, float* __restrict__ out) {
  const int p = blockIdx.x;
  const int g = p / 3, rem = p - 3 * g;
  if (rem == 0) {
    const int fp = g;                       // 0..2047
    const int b = fp >> 8, c = fp & 255;
    const float4* src = (const float4*)(x + ((size_t)b * CC + c) * HW);
    float4* dst = (float4*)(out + ((size_t)b * OC + c) * HW);
#pragma unroll
    for (int u = 0; u < 4; ++u) {
      const int t = threadIdx.x + u * 256;
      dst[t] = src[t];
    }
    return;
  }
  const int i = 2 * g + (rem - 1);          // 0..4095
  if (mask[i] == 0) {
    if (threadIdx.x == 0) idx[i] = -1;
    return;
  }

  __shared__ int cols[HW];                  // compacted unflagged columns
  __shared__ int chunk_cnt[64];
  __shared__ int chunk_off[64];
  __shared__ int total_sh;
  __shared__ long long sred[4];
  const int wave = threadIdx.x >> 6;
  const int lane = threadIdx.x & 63;

  // 64 chunks of 64 columns; wave w handles chunks w, w+4, ...
#pragma unroll
  for (int t = wave; t < 64; t += 4) {
    const int j = t * 64 + lane;
    const unsigned long long bal = __ballot(mask[j] == 0);
    if (lane == 0) chunk_cnt[t] = __popcll(bal);
  }
  __syncthreads();
  if (wave == 0) {                          // 64-wide scan in one wave
    int v = chunk_cnt[lane];
    int inc = v;
#pragma unroll
    for (int off = 1; off < 64; off <<= 1) {
      const int u = __shfl_up(inc, off);
      if (lane >= off) inc += u;
    }
    chunk_off[lane] = inc - v;              // exclusive
    if (lane == 63) total_sh = inc;
  }
  __syncthreads();
#pragma unroll
  for (int t = wave; t < 64; t += 4) {
    const int j = t * 64 + lane;
    const bool un = (mask[j] == 0);
    const unsigned long long bal = __ballot(un);
    if (un) {
      const int pos = chunk_off[t] + __popcll(bal & ((1ULL << lane) - 1ULL));
      cols[pos] = j;
    }
  }
  __syncthreads();

  const int m = total_sh;
  const uint32_t e0 = (uint32_t)i << 12;
  long long best = -1;                      // ((bits>>9) << 12) | (4095 - j)
  for (int t = threadIdx.x; t < m; t += 256) {
    const int j = cols[t];
    const uint32_t bits = jax_bits32(e0 + (uint32_t)j);
    const long long k = ((long long)(bits >> 9) << 12) | (long long)(4095 - j);
    best = (k > best) ? k : best;
  }
#pragma unroll
  for (int off = 32; off > 0; off >>= 1) {
    const long long a = __shfl_down(best, off);
    best = (a > best) ? a : best;
  }
  if (lane == 0) sred[wave] = best;
  __syncthreads();
  if (threadIdx.x == 0) {
    long long a = sred[0];
#pragma unroll
    for (int w = 1; w < 4; ++w) if (sred[w] > a) a = sred[w];
    // m==0 (all columns NEG_INF) -> argmax = 0, matches reference.
    idx[i] = (a >= 0) ? (4095 - (int)(a & 0xFFFLL)) : 0;
  }
}

// ---------------------------------------------------------------------------
// Kernel B (2048 blocks): latter plane (b,c), c in [0,256): stage x[b,256+c]
// in LDS once; write BOTH the copy out[b,256+c] and the gather out[b,512+c]
// (single HBM fetch of the latter half — no re-read anywhere).
__global__ __launch_bounds__(256) void latter_kernel(const float* __restrict__ x,
                                                     const int* __restrict__ idx,
                                                     float* __restrict__ out) {
  const int p = blockIdx.x;                 // 0..2047
  const int b = p >> 8, c = p & 255;
  const float* row = x + ((size_t)b * CC + C2 + c) * HW;
  float* ocopy  = out + ((size_t)b * OC + 256 + c) * HW;
  float* oshift = out + ((size_t)b * OC + 512 + c) * HW;
  __shared__ float lds[HW];
  const float4* row4 = (const float4*)row;
  float4* lds4 = (float4*)lds;
  float4* ocopy4 = (float4*)ocopy;
#pragma unroll
  for (int u = 0; u < 4; ++u) {
    const int t = threadIdx.x + u * 256;
    const float4 v = row4[t];
    lds4[t] = v;
    ocopy4[t] = v;                          // copy while staging
  }
  __syncthreads();
  const int4* idx4 = (const int4*)idx;
  float4* oshift4 = (float4*)oshift;
#pragma unroll
  for (int u = 0; u < 4; ++u) {
    const int t = threadIdx.x + u * 256;
    const int4 nb = idx4[t];
    float4 v;
    v.x = (nb.x >= 0) ? lds[nb.x] : 0.0f;
    v.y = (nb.y >= 0) ? lds[nb.y] : 0.0f;
    v.z = (nb.z >= 0) ? lds[nb.z] : 0.0f;
    v.w = (nb.w >= 0) ? lds[nb.w] : 0.0f;
    oshift4[t] = v;
  }
}

extern "C" void kernel_launch(void* const* d_in, const int* in_sizes, int n_in,
                              void* d_out, int out_size, void* d_ws, size_t ws_size,
                              hipStream_t stream) {
  const float* x  = (const float*)d_in[0];
  const int* mask = (const int*)d_in[1];
  float* out      = (float*)d_out;
  int* idx        = (int*)d_ws;             // [4096]

  former_argmax_kernel<<<6144, 256, 0, stream>>>(x, mask, idx, out);
  latter_kernel<<<2048, 256, 0, stream>>>(x, idx, out);
}

// Round 8
// 162.393 us; speedup vs baseline: 1.0340x; 1.0340x over previous
//
#include <hip/hip_runtime.h>
#include <stdint.h>

// x (8, 512, 64, 64) fp32, mask (64, 64) int32 -> out (8, 768, 64, 64) fp32
static constexpr int HW = 4096;   // 64*64
static constexpr int CC = 512;
static constexpr int C2 = 256;
static constexpr int OC = 768;

__device__ __forceinline__ uint32_t rotl32(uint32_t x, int d) {
  return (x << d) | (x >> (32 - d));
}

// JAX threefry2x32, key (0, 42)  [jax.random.key(42)]
__device__ __forceinline__ void threefry_0_42(uint32_t x0, uint32_t x1,
                                              uint32_t& o0, uint32_t& o1) {
  const uint32_t k0 = 0u;
  const uint32_t k1 = 42u;
  const uint32_t k2 = 0x1BD11BDAu ^ k0 ^ k1;   // 0x1BD11BF0
  x0 += k0; x1 += k1;
#define TF_ROUND(r) { x0 += x1; x1 = rotl32(x1, (r)); x1 ^= x0; }
  TF_ROUND(13) TF_ROUND(15) TF_ROUND(26) TF_ROUND(6)
  x0 += k1; x1 += k2 + 1u;
  TF_ROUND(17) TF_ROUND(29) TF_ROUND(16) TF_ROUND(24)
  x0 += k2; x1 += k0 + 2u;
  TF_ROUND(13) TF_ROUND(15) TF_ROUND(26) TF_ROUND(6)
  x0 += k0; x1 += k1 + 3u;
  TF_ROUND(17) TF_ROUND(29) TF_ROUND(16) TF_ROUND(24)
  x0 += k1; x1 += k2 + 4u;
  TF_ROUND(13) TF_ROUND(15) TF_ROUND(26) TF_ROUND(6)
  x0 += k2; x1 += k0 + 5u;
#undef TF_ROUND
  o0 = x0; o1 = x1;
}

// Partitionable threefry: counter (0, e), fold = xor of the two output lanes.
__device__ __forceinline__ uint32_t jax_bits32(uint32_t e) {
  uint32_t o0, o1;
  threefry_0_42(0u, e, o0, o1);
  return o0 ^ o1;
}

// ---------------------------------------------------------------------------
// Kernel A (8192 blocks, roles interleaved even/odd for VALU/mem co-schedule):
//   even p: copy plane q=p/2 in [0,4096): out[b,ch] = x[b,ch], ch in [0,512)
//   odd  p: score-matrix row i=p/2 in [0,4096):
//     flag[i]==0 -> idx[i]=-1 (reference discards this row's argmax)
//     else: per-block ballot compaction of unflagged columns into LDS, then
//           exact-integer argmax of partitionable-threefry bits (monotone in
//           bits>>9), tie -> smallest j via packed key.
__global__ __launch_bounds__(256) void copy_argmax_kernel(
    const float* __restrict__ x, const int* __restrict__ mask,
    int* __restrict__ idx, float* __restrict__ out) {
  const int p = blockIdx.x;
  if ((p & 1) == 0) {
    const int q = p >> 1;                   // 0..4095 copy planes
    const int b = q >> 9, ch = q & 511;
    const float4* src = (const float4*)(x + ((size_t)b * CC + ch) * HW);
    float4* dst = (float4*)(out + ((size_t)b * OC + ch) * HW);
#pragma unroll
    for (int r = 0; r < 4; ++r) {
      const int t = threadIdx.x + r * 256;
      dst[t] = src[t];
    }
    return;
  }
  const int i = p >> 1;                     // 0..4095 rows
  if (mask[i] == 0) {
    if (threadIdx.x == 0) idx[i] = -1;
    return;
  }

  __shared__ int cols[HW];                  // compacted unflagged columns
  __shared__ int chunk_cnt[64];
  __shared__ int chunk_off[64];
  __shared__ int total_sh;
  const int wave = threadIdx.x >> 6;
  const int lane = threadIdx.x & 63;

  // 64 chunks of 64 columns each; wave w handles chunks w, w+4, ...
#pragma unroll
  for (int t = wave; t < 64; t += 4) {
    const int j = t * 64 + lane;
    const unsigned long long bal = __ballot(mask[j] == 0);
    if (lane == 0) chunk_cnt[t] = __popcll(bal);
  }
  __syncthreads();
  if (wave == 0) {                          // 64-element scan by one wave
    int v = chunk_cnt[lane];
    int inc = v;
#pragma unroll
    for (int off = 1; off < 64; off <<= 1) {
      const int u = __shfl_up(inc, off);
      if (lane >= off) inc += u;
    }
    chunk_off[lane] = inc - v;              // exclusive
    if (lane == 63) total_sh = inc;
  }
  __syncthreads();
#pragma unroll
  for (int t = wave; t < 64; t += 4) {
    const int j = t * 64 + lane;
    const bool un = (mask[j] == 0);
    const unsigned long long bal = __ballot(un);
    if (un) {
      const int pos = chunk_off[t] + __popcll(bal & ((1ULL << lane) - 1ULL));
      cols[pos] = j;
    }
  }
  __syncthreads();

  const int m = total_sh;
  const uint32_t e0 = (uint32_t)i * 4096u;
  long long best = -1;                      // ((bits>>9) << 12) | (4095 - j)
  for (int t = threadIdx.x; t < m; t += 256) {
    const int j = cols[t];
    const uint32_t bits = jax_bits32(e0 + (uint32_t)j);
    const long long k = ((long long)(bits >> 9) << 12) | (long long)(4095 - j);
    best = (k > best) ? k : best;
  }
#pragma unroll
  for (int off = 32; off > 0; off >>= 1) {
    const long long a = __shfl_down(best, off);
    best = (a > best) ? a : best;
  }
  __shared__ long long s[4];
  if (lane == 0) s[wave] = best;
  __syncthreads();
  if (threadIdx.x == 0) {
    long long a = s[0];
#pragma unroll
    for (int w = 1; w < 4; ++w) if (s[w] > a) a = s[w];
    // m==0 (all columns NEG_INF) -> argmax==0, matches reference.
    idx[i] = (a >= 0) ? (4095 - (int)(a & 0xFFFLL)) : 0;
  }
}

// ---------------------------------------------------------------------------
// Kernel B (2048 blocks): shift planes (b,c), c in [0,256):
//   out[b,512+c,j] = idx[j]>=0 ? x[b,256+c,idx[j]] : 0
// The 33.5 MB re-read of x's latter half is L3-resident after kernel A.
__global__ __launch_bounds__(256) void gather_kernel(const float* __restrict__ x,
                                                     const int* __restrict__ idx,
                                                     float* __restrict__ out) {
  const int p = blockIdx.x;
  const int b = p >> 8, c = p & 255;
  const float* row = x + ((size_t)b * CC + C2 + c) * HW;
  float* oshift = out + ((size_t)b * OC + 512 + c) * HW;
  __shared__ float lds[HW];
  const float4* row4 = (const float4*)row;
  float4* lds4 = (float4*)lds;
#pragma unroll
  for (int r = 0; r < 4; ++r) {
    const int t = threadIdx.x + r * 256;
    lds4[t] = row4[t];
  }
  __syncthreads();
  const int4* idx4 = (const int4*)idx;
  float4* oshift4 = (float4*)oshift;
#pragma unroll
  for (int r = 0; r < 4; ++r) {
    const int t = threadIdx.x + r * 256;
    const int4 nb = idx4[t];
    float4 v;
    v.x = (nb.x >= 0) ? lds[nb.x] : 0.0f;
    v.y = (nb.y >= 0) ? lds[nb.y] : 0.0f;
    v.z = (nb.z >= 0) ? lds[nb.z] : 0.0f;
    v.w = (nb.w >= 0) ? lds[nb.w] : 0.0f;
    oshift4[t] = v;
  }
}

extern "C" void kernel_launch(void* const* d_in, const int* in_sizes, int n_in,
                              void* d_out, int out_size, void* d_ws, size_t ws_size,
                              hipStream_t stream) {
  const float* x  = (const float*)d_in[0];
  const int* mask = (const int*)d_in[1];
  float* out      = (float*)d_out;
  int* idx        = (int*)d_ws;             // [4096]

  copy_argmax_kernel<<<8192, 256, 0, stream>>>(x, mask, idx, out);
  gather_kernel<<<2048, 256, 0, stream>>>(x, idx, out);
}